// Round 1
// baseline (454.182 us; speedup 1.0000x reference)
//
#include <hip/hip_runtime.h>
#include <math.h>

#define BB 8
#define NN 4096
#define DD 2048
#define DLL 64
#define NCLS 2

// ---- K1: dis[b,n] = (sum_l tanh(x[b,n,:]@V[:,l]) * W[l]) / sqrt(64), masked ----
// block: 64 rows x 64 cols, BK=64, 256 threads, 4x4 register tile per thread.
constexpr int RPB = 64;   // rows per block
constexpr int BK  = 64;   // k-chunk
constexpr int XP  = 68;   // padded X tile row (floats); 68*4=272B, 16B-aligned

__global__ __launch_bounds__(256) void k1_dis(const float* __restrict__ x,
                                              const int* __restrict__ true_num,
                                              const float* __restrict__ V,
                                              const float* __restrict__ W,
                                              float* __restrict__ dis) {
    __shared__ float Xs[RPB][XP];   // [row][k]
    __shared__ float Vs[BK][DLL];   // [k][l]
    __shared__ float Ws[DLL];

    const int tid  = threadIdx.x;
    const int blk  = blockIdx.x;                 // 0..511
    const long row0 = (long)blk * RPB;           // global flat row = b*N + n
    const int b    = (int)(row0 / NN);
    const int n0   = (int)(row0 % NN);
    const int tn   = true_num[b];

    // fully-masked block: write -1e20 and skip all work (uniform branch, before any sync)
    if (n0 >= tn) {
        if (tid < RPB) dis[row0 + tid] = -1e20f;
        return;
    }

    if (tid < DLL) Ws[tid] = W[tid];

    const int c  = tid & 15;    // col group: cols 4c..4c+3
    const int rg = tid >> 4;    // row group: rows 4rg..4rg+3

    float acc[4][4];
    #pragma unroll
    for (int i = 0; i < 4; i++)
        #pragma unroll
        for (int j = 0; j < 4; j++) acc[i][j] = 0.f;

    for (int k0 = 0; k0 < DD; k0 += BK) {
        // stage X tile: 64 rows x 64 k = 1024 float4
        #pragma unroll
        for (int i = 0; i < 4; i++) {
            int e = tid + i * 256;     // 0..1023
            int q = e & 15;            // float4 within row
            int r = e >> 4;            // row
            float4 v = *(const float4*)(x + (row0 + r) * DD + k0 + 4 * q);
            *(float4*)&Xs[r][4 * q] = v;
        }
        // stage V tile: 64 k x 64 l = 1024 float4 (fully contiguous)
        #pragma unroll
        for (int i = 0; i < 4; i++) {
            int e = tid + i * 256;
            int q = e & 15;
            int k = e >> 4;
            float4 v = *(const float4*)(V + (long)(k0 + k) * DLL + 4 * q);
            *(float4*)&Vs[k][4 * q] = v;
        }
        __syncthreads();

        #pragma unroll 4
        for (int kk = 0; kk < BK; kk += 4) {
            float4 xr[4], vc[4];
            #pragma unroll
            for (int i = 0; i < 4; i++) xr[i] = *(const float4*)&Xs[4 * rg + i][kk];
            #pragma unroll
            for (int j = 0; j < 4; j++) vc[j] = *(const float4*)&Vs[kk + j][4 * c];
            #pragma unroll
            for (int i = 0; i < 4; i++) {
                const float* xp = (const float*)&xr[i];
                #pragma unroll
                for (int j = 0; j < 4; j++) {
                    const float* vp = (const float*)&vc[j];
                    #pragma unroll
                    for (int m = 0; m < 4; m++)
                        acc[i][m] = fmaf(xp[j], vp[m], acc[i][m]);
                }
            }
        }
        __syncthreads();
    }

    // epilogue: dis per row. Thread holds rows 4rg..4rg+3, cols 4c..4c+3.
    float w0 = Ws[4 * c], w1 = Ws[4 * c + 1], w2 = Ws[4 * c + 2], w3 = Ws[4 * c + 3];
    #pragma unroll
    for (int i = 0; i < 4; i++) {
        float p = tanhf(acc[i][0]) * w0 + tanhf(acc[i][1]) * w1 +
                  tanhf(acc[i][2]) * w2 + tanhf(acc[i][3]) * w3;
        // reduce across 16 lanes sharing the same row group (lane = rg_local*16 + c)
        #pragma unroll
        for (int off = 8; off >= 1; off >>= 1) p += __shfl_xor(p, off, 64);
        if (c == 0) {
            int n = n0 + 4 * rg + i;
            float dv = p * 0.125f;        // 1/sqrt(64)
            if (n >= tn) dv = -1e20f;
            dis[(long)b * NN + n] = dv;
        }
    }
}

// ---- K2: per-batch softmax over N -> soft_assign ----
__global__ __launch_bounds__(256) void k2_softmax(const float* __restrict__ dis,
                                                  float* __restrict__ soft) {
    __shared__ float red[4];
    __shared__ float bcast;
    const int b = blockIdx.x, t = threadIdx.x;
    const float* db = dis + (size_t)b * NN;

    float m = -3.4e38f;
    for (int i = t; i < NN; i += 256) m = fmaxf(m, db[i]);
    #pragma unroll
    for (int o = 32; o >= 1; o >>= 1) m = fmaxf(m, __shfl_xor(m, o, 64));
    if ((t & 63) == 0) red[t >> 6] = m;
    __syncthreads();
    if (t == 0) bcast = fmaxf(fmaxf(red[0], red[1]), fmaxf(red[2], red[3]));
    __syncthreads();
    const float M = bcast;

    float s = 0.f;
    for (int i = t; i < NN; i += 256) s += expf(db[i] - M);
    #pragma unroll
    for (int o = 32; o >= 1; o >>= 1) s += __shfl_xor(s, o, 64);
    if ((t & 63) == 0) red[t >> 6] = s;
    __syncthreads();
    if (t == 0) bcast = 1.f / (red[0] + red[1] + red[2] + red[3]);
    __syncthreads();
    const float inv = bcast;

    for (int i = t; i < NN; i += 256)
        soft[(size_t)b * NN + i] = expf(db[i] - M) * inv;
}

// ---- K3: per-64-row-block weighted partial sums: partial[blk][d] = sum_r a_r * x[r][d] ----
__global__ __launch_bounds__(256) void k3_partial(const float* __restrict__ x,
                                                  const float* __restrict__ soft,
                                                  float* __restrict__ partial) {
    __shared__ float as[RPB];
    const int blk = blockIdx.x;              // 0..511
    const long row0 = (long)blk * RPB;       // flat row
    const int t = threadIdx.x;

    if (t < RPB) as[t] = soft[row0 + t];
    __syncthreads();

    float4 a0 = {0.f, 0.f, 0.f, 0.f}, a1 = {0.f, 0.f, 0.f, 0.f};
    const float4* xb = (const float4*)(x + row0 * DD);
    for (int r = 0; r < RPB; r++) {
        float a = as[r];
        if (a != 0.f) {
            float4 v0 = xb[(size_t)r * 512 + t];
            float4 v1 = xb[(size_t)r * 512 + t + 256];
            a0.x = fmaf(a, v0.x, a0.x); a0.y = fmaf(a, v0.y, a0.y);
            a0.z = fmaf(a, v0.z, a0.z); a0.w = fmaf(a, v0.w, a0.w);
            a1.x = fmaf(a, v1.x, a1.x); a1.y = fmaf(a, v1.y, a1.y);
            a1.z = fmaf(a, v1.z, a1.z); a1.w = fmaf(a, v1.w, a1.w);
        }
    }
    float* pb = partial + (size_t)blk * DD;
    ((float4*)pb)[t] = a0;
    ((float4*)pb)[t + 256] = a1;
}

// ---- K4: combine 64 partials per batch -> feat -> logits -> cls_probs ----
__global__ __launch_bounds__(256) void k4_final(const float* __restrict__ partial,
                                                const float* __restrict__ fc_w,
                                                const float* __restrict__ fc_b,
                                                float* __restrict__ cls) {
    __shared__ float red0[4], red1[4];
    const int b = blockIdx.x, t = threadIdx.x;

    float4 f0 = {0.f, 0.f, 0.f, 0.f}, f1 = {0.f, 0.f, 0.f, 0.f};
    const float* pb = partial + (size_t)b * 64 * DD;
    for (int p = 0; p < 64; p++) {
        const float4* row = (const float4*)(pb + (size_t)p * DD);
        float4 v0 = row[t], v1 = row[t + 256];
        f0.x += v0.x; f0.y += v0.y; f0.z += v0.z; f0.w += v0.w;
        f1.x += v1.x; f1.y += v1.y; f1.z += v1.z; f1.w += v1.w;
    }
    // logits: thread covers d = 4t..4t+3 and 1024+4t..1024+4t+3
    const float4 w00 = ((const float4*)fc_w)[t];
    const float4 w01 = ((const float4*)fc_w)[t + 256];
    const float4 w10 = ((const float4*)(fc_w + DD))[t];
    const float4 w11 = ((const float4*)(fc_w + DD))[t + 256];
    float l0 = f0.x * w00.x + f0.y * w00.y + f0.z * w00.z + f0.w * w00.w +
               f1.x * w01.x + f1.y * w01.y + f1.z * w01.z + f1.w * w01.w;
    float l1 = f0.x * w10.x + f0.y * w10.y + f0.z * w10.z + f0.w * w10.w +
               f1.x * w11.x + f1.y * w11.y + f1.z * w11.z + f1.w * w11.w;
    #pragma unroll
    for (int o = 32; o >= 1; o >>= 1) {
        l0 += __shfl_xor(l0, o, 64);
        l1 += __shfl_xor(l1, o, 64);
    }
    if ((t & 63) == 0) { red0[t >> 6] = l0; red1[t >> 6] = l1; }
    __syncthreads();
    if (t == 0) {
        float L0 = red0[0] + red0[1] + red0[2] + red0[3] + fc_b[0];
        float L1 = red1[0] + red1[1] + red1[2] + red1[3] + fc_b[1];
        float mm = fmaxf(L0, L1);
        float e0 = expf(L0 - mm), e1 = expf(L1 - mm);
        float inv = 1.f / (e0 + e1);
        cls[b * 2 + 0] = e0 * inv;
        cls[b * 2 + 1] = e1 * inv;
    }
}

extern "C" void kernel_launch(void* const* d_in, const int* in_sizes, int n_in,
                              void* d_out, int out_size, void* d_ws, size_t ws_size,
                              hipStream_t stream) {
    const float* x        = (const float*)d_in[0];
    const int*   true_num = (const int*)d_in[1];
    const float* V        = (const float*)d_in[2];
    const float* W        = (const float*)d_in[3];
    const float* fc_w     = (const float*)d_in[4];
    const float* fc_b     = (const float*)d_in[5];

    float* out  = (float*)d_out;
    float* cls  = out;                       // B*NCLS = 16 floats
    float* soft = out + BB * NCLS;           // B*N = 32768 floats

    float* dis     = (float*)d_ws;                       // B*N floats
    float* partial = dis + (size_t)BB * NN;              // 512*2048 floats (4 MB)

    const int nblocks = (BB * NN) / RPB;     // 512

    k1_dis<<<nblocks, 256, 0, stream>>>(x, true_num, V, W, dis);
    k2_softmax<<<BB, 256, 0, stream>>>(dis, soft);
    k3_partial<<<nblocks, 256, 0, stream>>>(x, soft, partial);
    k4_final<<<BB, 256, 0, stream>>>(partial, fc_w, fc_b, cls);
}

// Round 2
// 412.881 us; speedup vs baseline: 1.1000x; 1.1000x over previous
//
#include <hip/hip_runtime.h>
#include <hip/hip_bf16.h>
#include <math.h>

#define BB 8
#define NN 4096
#define DD 2048
#define DLL 64
#define NCLS 2

typedef __attribute__((ext_vector_type(8))) short bf16x8;
typedef __attribute__((ext_vector_type(4))) float f32x4;

// fp32 -> bf16 round-to-nearest-even (inputs are finite randoms; no NaN path)
__device__ __forceinline__ short f2bf(float f) {
    unsigned int u = __float_as_uint(f);
    unsigned int r = (u + 0x7fffu + ((u >> 16) & 1u)) >> 16;
    return (short)r;
}
__device__ __forceinline__ float bf2f(short s) {
    return __uint_as_float(((unsigned int)(unsigned short)s) << 16);
}

// ---- K0: V (2048x64 fp32) -> Vt bf16 [64][2048] (transposed, for MFMA B-frags) ----
__global__ __launch_bounds__(256) void k_cvt_v(const float* __restrict__ V,
                                               short* __restrict__ Vt) {
    int e = blockIdx.x * 256 + threadIdx.x;   // 0..131071, coalesced read
    int k = e >> 6, l = e & 63;
    Vt[(size_t)l * DD + k] = f2bf(V[e]);
}

// ---- K1: fused dis-GEMM + block-local online-softmax partial sums ----
// grid 2048 (= B * N/16), 256 threads. Tile: 16 rows x D. x read ONCE.
// LDS: x tile as bf16 [16][2048], 16B-chunk XOR-swizzled by (row&7).
__global__ __launch_bounds__(256, 2) void k_fused(
        const float* __restrict__ x, const int* __restrict__ tn_p,
        const short* __restrict__ Vt, const float* __restrict__ W,
        float* __restrict__ dis, float* __restrict__ mblk,
        float* __restrict__ lblk, float* __restrict__ partial,
        float* __restrict__ dpart, float* __restrict__ erow_g) {
    __shared__ short Xs[16 * 2048];   // exactly 64 KiB -> 2 blocks/CU

    const int tid = threadIdx.x;
    const int blk = blockIdx.x;
    const int b  = blk >> 8;
    const int n0 = (blk & 255) << 4;
    const int tn = tn_p[b];
    if (n0 >= tn) return;             // fully-masked tile: no work, nothing read later

    // ---- stage: 16 rows x 2048 fp32 -> bf16 LDS (coalesced 1KB/wave-instr) ----
    const float4* xsrc = (const float4*)(x + ((size_t)(b * NN + n0)) * DD);
    #pragma unroll 8
    for (int i = 0; i < 32; i++) {
        int e = tid + (i << 8);           // 0..8191 float4s
        int row = e >> 9, f4 = e & 511;
        float4 v = xsrc[(size_t)row * 512 + f4];
        int c = f4 >> 1, h = f4 & 1;      // 16B chunk, half
        int sc = c ^ (row & 7);           // swizzle
        short4 s;
        s.x = f2bf(v.x); s.y = f2bf(v.y); s.z = f2bf(v.z); s.w = f2bf(v.w);
        *(short4*)&Xs[row * 2048 + sc * 8 + h * 4] = s;
    }
    __syncthreads();

    // ---- GEMM: wave w -> cols 16w..16w+15; A from LDS, B from L2-resident Vt ----
    const int lane = tid & 63, w = tid >> 6;
    const int mm = lane & 15, q = lane >> 4;
    const short* brow = Vt + (size_t)(w * 16 + mm) * DD + q * 8;
    const int arowbase = mm * 2048;
    const int msw = mm & 7;
    f32x4 acc = {0.f, 0.f, 0.f, 0.f};
    #pragma unroll 4
    for (int kc = 0; kc < 64; kc++) {
        int c = kc * 4 + q;
        bf16x8 a  = *(const bf16x8*)&Xs[arowbase + ((c ^ msw) << 3)];
        bf16x8 bv = *(const bf16x8*)(brow + kc * 32);
        acc = __builtin_amdgcn_mfma_f32_16x16x32_bf16(a, bv, acc, 0, 0, 0);
    }

    // ---- epilogue: dis rows; C layout col=lane&15, row=(lane>>4)*4+reg ----
    const float wl = W[w * 16 + mm];
    float* dpb = dpart + blk * 64;
    #pragma unroll
    for (int r = 0; r < 4; r++) {
        float p = tanhf(acc[r]) * wl;
        p += __shfl_xor(p, 1, 64);
        p += __shfl_xor(p, 2, 64);
        p += __shfl_xor(p, 4, 64);
        p += __shfl_xor(p, 8, 64);
        if (mm == 0) dpb[w * 16 + q * 4 + r] = p;   // per-wave partial col-sum
    }
    __syncthreads();   // drains global writes; block-visible via same-CU L1

    if (w == 0) {
        float d = (dpb[mm] + dpb[16 + mm] + dpb[32 + mm] + dpb[48 + mm]) * 0.125f;
        int n = n0 + mm;
        if (n >= tn) d = -1e20f;                    // in-tile masked rows
        if (lane < 16) dis[b * NN + n] = d;
        float mx = d;
        mx = fmaxf(mx, __shfl_xor(mx, 1, 64));
        mx = fmaxf(mx, __shfl_xor(mx, 2, 64));
        mx = fmaxf(mx, __shfl_xor(mx, 4, 64));
        mx = fmaxf(mx, __shfl_xor(mx, 8, 64));
        float e = expf(d - mx);                     // masked -> exp(-1e20)=0
        float ls = e;
        ls += __shfl_xor(ls, 1, 64);
        ls += __shfl_xor(ls, 2, 64);
        ls += __shfl_xor(ls, 4, 64);
        ls += __shfl_xor(ls, 8, 64);
        if (lane < 16) erow_g[blk * 16 + lane] = e;
        if (lane == 0) { mblk[blk] = mx; lblk[blk] = ls; }
    }
    __syncthreads();

    // ---- weighted partial: partial[d] = sum_r e_r * x[r][d], from LDS tile ----
    float er[16];
    const float* eg = erow_g + blk * 16;
    #pragma unroll
    for (int r = 0; r < 16; r++) er[r] = eg[r];

    float facc[8];
    #pragma unroll
    for (int u = 0; u < 8; u++) facc[u] = 0.f;
    #pragma unroll
    for (int r = 0; r < 16; r++) {
        bf16x8 sv = *(const bf16x8*)&Xs[r * 2048 + ((tid ^ (r & 7)) << 3)];
        float e = er[r];
        #pragma unroll
        for (int u = 0; u < 8; u++) facc[u] = fmaf(e, bf2f(sv[u]), facc[u]);
    }
    float* pdst = partial + (size_t)blk * DD + tid * 8;
    float4 o0 = {facc[0], facc[1], facc[2], facc[3]};
    float4 o1 = {facc[4], facc[5], facc[6], facc[7]};
    *(float4*)pdst = o0;
    *(float4*)(pdst + 4) = o1;
}

// ---- K2: per-batch combine m/l across blocks -> M, L, per-block alpha ----
__global__ __launch_bounds__(256) void k_ml(const int* __restrict__ tn_p,
        const float* __restrict__ mblk, const float* __restrict__ lblk,
        float* __restrict__ alpha, float* __restrict__ MbA,
        float* __restrict__ iLbA) {
    __shared__ float red[4];
    __shared__ float bc;
    const int b = blockIdx.x, t = threadIdx.x;
    const int nvb = (tn_p[b] + 15) >> 4;        // valid tiles, 1..256
    const float mt = (t < nvb) ? mblk[b * 256 + t] : -3.4e38f;
    float mx = mt;
    #pragma unroll
    for (int o = 32; o >= 1; o >>= 1) mx = fmaxf(mx, __shfl_xor(mx, o, 64));
    if ((t & 63) == 0) red[t >> 6] = mx;
    __syncthreads();
    if (t == 0) bc = fmaxf(fmaxf(red[0], red[1]), fmaxf(red[2], red[3]));
    __syncthreads();
    const float M = bc;
    const float sc = (t < nvb) ? expf(mt - M) : 0.f;
    float ls = (t < nvb) ? sc * lblk[b * 256 + t] : 0.f;
    #pragma unroll
    for (int o = 32; o >= 1; o >>= 1) ls += __shfl_xor(ls, o, 64);
    __syncthreads();
    if ((t & 63) == 0) red[t >> 6] = ls;
    __syncthreads();
    if (t == 0) bc = red[0] + red[1] + red[2] + red[3];
    __syncthreads();
    const float L = bc;
    if (t < nvb) alpha[b * 256 + t] = sc / L;
    if (t == 0) { MbA[b] = M; iLbA[b] = 1.f / L; }
}

// ---- K3: soft_assign = exp(dis - M)/L for valid n, else exact 0 ----
__global__ __launch_bounds__(256) void k_soft(const float* __restrict__ dis,
        const int* __restrict__ tn_p, const float* __restrict__ MbA,
        const float* __restrict__ iLbA, float* __restrict__ soft) {
    int e = blockIdx.x * 256 + threadIdx.x;   // float4 index, 0..8191
    int b = e >> 10;
    int n = (e & 1023) * 4;
    int tn = tn_p[b];
    float M = MbA[b], iL = iLbA[b];
    float4 dv = ((const float4*)dis)[e];
    float4 o;
    o.x = (n + 0 < tn) ? expf(dv.x - M) * iL : 0.f;
    o.y = (n + 1 < tn) ? expf(dv.y - M) * iL : 0.f;
    o.z = (n + 2 < tn) ? expf(dv.z - M) * iL : 0.f;
    o.w = (n + 3 < tn) ? expf(dv.w - M) * iL : 0.f;
    ((float4*)soft)[e] = o;
}

// ---- K4: feat[b][d] = sum_blk alpha_blk * partial[blk][d] ----
__global__ __launch_bounds__(256) void k_feat(const int* __restrict__ tn_p,
        const float* __restrict__ alpha, const float* __restrict__ partial,
        float* __restrict__ feat) {
    const int b = blockIdx.x >> 3, s = blockIdx.x & 7, t = threadIdx.x;
    const int nvb = (tn_p[b] + 15) >> 4;
    const int d = s * 256 + t;
    const float* ap = alpha + b * 256;
    const float* pp = partial + ((size_t)b * 256) * DD + d;
    float f = 0.f;
    int i = 0;
    for (; i + 4 <= nvb; i += 4) {
        float f0 = ap[i]     * pp[(size_t)i * DD];
        float f1 = ap[i + 1] * pp[(size_t)(i + 1) * DD];
        float f2 = ap[i + 2] * pp[(size_t)(i + 2) * DD];
        float f3 = ap[i + 3] * pp[(size_t)(i + 3) * DD];
        f += f0 + f1 + f2 + f3;
    }
    for (; i < nvb; i++) f += ap[i] * pp[(size_t)i * DD];
    feat[(size_t)b * DD + d] = f;
}

// ---- K5: logits + 2-class softmax ----
__global__ __launch_bounds__(256) void k_cls(const float* __restrict__ feat,
        const float* __restrict__ fc_w, const float* __restrict__ fc_b,
        float* __restrict__ cls) {
    __shared__ float red0[4], red1[4];
    const int b = blockIdx.x, t = threadIdx.x;
    const float4* fv = (const float4*)(feat + (size_t)b * DD);
    float4 f0 = fv[t], f1 = fv[t + 256];
    const float4 w00 = ((const float4*)fc_w)[t];
    const float4 w01 = ((const float4*)fc_w)[t + 256];
    const float4 w10 = ((const float4*)(fc_w + DD))[t];
    const float4 w11 = ((const float4*)(fc_w + DD))[t + 256];
    float l0 = f0.x * w00.x + f0.y * w00.y + f0.z * w00.z + f0.w * w00.w +
               f1.x * w01.x + f1.y * w01.y + f1.z * w01.z + f1.w * w01.w;
    float l1 = f0.x * w10.x + f0.y * w10.y + f0.z * w10.z + f0.w * w10.w +
               f1.x * w11.x + f1.y * w11.y + f1.z * w11.z + f1.w * w11.w;
    #pragma unroll
    for (int o = 32; o >= 1; o >>= 1) {
        l0 += __shfl_xor(l0, o, 64);
        l1 += __shfl_xor(l1, o, 64);
    }
    if ((t & 63) == 0) { red0[t >> 6] = l0; red1[t >> 6] = l1; }
    __syncthreads();
    if (t == 0) {
        float L0 = red0[0] + red0[1] + red0[2] + red0[3] + fc_b[0];
        float L1 = red1[0] + red1[1] + red1[2] + red1[3] + fc_b[1];
        float mm = fmaxf(L0, L1);
        float e0 = expf(L0 - mm), e1 = expf(L1 - mm);
        float inv = 1.f / (e0 + e1);
        cls[b * 2 + 0] = e0 * inv;
        cls[b * 2 + 1] = e1 * inv;
    }
}

extern "C" void kernel_launch(void* const* d_in, const int* in_sizes, int n_in,
                              void* d_out, int out_size, void* d_ws, size_t ws_size,
                              hipStream_t stream) {
    (void)in_sizes; (void)n_in; (void)out_size; (void)ws_size;
    const float* x        = (const float*)d_in[0];
    const int*   true_num = (const int*)d_in[1];
    const float* V        = (const float*)d_in[2];
    const float* W        = (const float*)d_in[3];
    const float* fc_w     = (const float*)d_in[4];
    const float* fc_b     = (const float*)d_in[5];

    float* out  = (float*)d_out;
    float* cls  = out;                     // B*NCLS
    float* soft = out + BB * NCLS;         // B*N

    float* dis     = (float*)d_ws;                           // 32768
    float* mblk    = dis + BB * NN;                          // 2048
    float* lblk    = mblk + 2048;                            // 2048
    float* alpha   = lblk + 2048;                            // 2048
    float* MbA     = alpha + 2048;                           // 8
    float* iLbA    = MbA + 8;                                // 8
    float* feat    = iLbA + 8;                               // 16384
    float* dpart   = feat + BB * DD;                         // 2048*64
    float* erow    = dpart + 2048 * 64;                      // 2048*16
    float* partial = erow + 2048 * 16;                       // 2048*2048
    short* Vt      = (short*)(partial + (size_t)2048 * DD);  // 64*2048 bf16

    k_cvt_v<<<512, 256, 0, stream>>>(V, Vt);
    k_fused<<<2048, 256, 0, stream>>>(x, true_num, Vt, W, dis, mblk, lblk,
                                      partial, dpart, erow);
    k_ml<<<BB, 256, 0, stream>>>(true_num, mblk, lblk, alpha, MbA, iLbA);
    k_soft<<<32, 256, 0, stream>>>(dis, true_num, MbA, iLbA, soft);
    k_feat<<<64, 256, 0, stream>>>(true_num, alpha, partial, feat);
    k_cls<<<BB, 256, 0, stream>>>(feat, fc_w, fc_b, cls);
}

// Round 3
// 359.163 us; speedup vs baseline: 1.2646x; 1.1496x over previous
//
#include <hip/hip_runtime.h>
#include <math.h>

#define BB 8
#define NN 4096
#define DD 2048

typedef __attribute__((ext_vector_type(8))) short bf16x8;
typedef __attribute__((ext_vector_type(4))) float f32x4;

// fp32 -> bf16 round-to-nearest-even (inputs are finite randoms; no NaN path)
__device__ __forceinline__ short f2bf(float f) {
    unsigned int u = __float_as_uint(f);
    unsigned int r = (u + 0x7fffu + ((u >> 16) & 1u)) >> 16;
    return (short)r;
}
__device__ __forceinline__ float bf2f(short s) {
    return __uint_as_float(((unsigned int)(unsigned short)s) << 16);
}

// ---- K0: pack V (2048x64 fp32) into MFMA B-frag order + zero qblk ----
// Vp[((w*64+kc)*64 + lane)*8 + j] = bf16(V[kc*32 + (lane>>4)*8 + j][w*16 + (lane&15)])
__global__ __launch_bounds__(256) void k_pack_v(const float* __restrict__ V,
                                                short* __restrict__ Vp,
                                                float* __restrict__ qblk) {
    int e = blockIdx.x * 256 + threadIdx.x;    // 0..16383
    if (e < 4096) qblk[e] = 0.f;               // zero atomic targets
    int lane = e & 63, kc = (e >> 6) & 63, w = e >> 12;
    int q = lane >> 4, mm = lane & 15;
    int kb = kc * 32 + q * 8, l = w * 16 + mm;
    bf16x8 o;
    #pragma unroll
    for (int j = 0; j < 8; j++) o[j] = f2bf(V[(size_t)(kb + j) * 64 + l]);
    *(bf16x8*)(Vp + (size_t)e * 8) = o;
}

// ---- K1: fused dis-GEMM + block-local online-softmax + e-weighted q-dots ----
// grid 2048 (= B * N/16), 256 threads; x read ONCE; LDS x-tile bf16, XOR-swizzled.
__global__ __launch_bounds__(256, 2) void k_fused(
        const float* __restrict__ x, const int* __restrict__ tn_p,
        const short* __restrict__ Vp, const float* __restrict__ W,
        const float* __restrict__ fc_w,
        float* __restrict__ dis, float* __restrict__ mblk,
        float* __restrict__ lblk, float* __restrict__ qblk,
        float* __restrict__ dpart, float* __restrict__ erow_g) {
    __shared__ short Xs[16 * 2048];   // exactly 64 KiB -> 2 blocks/CU

    const int tid = threadIdx.x;
    const int blk = blockIdx.x;
    const int b  = blk >> 8;
    const int n0 = (blk & 255) << 4;
    const int tn = tn_p[b];
    if (n0 >= tn) return;             // fully-masked tile

    // ---- stage: 16 rows x 2048 fp32 -> bf16 LDS ----
    const float4* xsrc = (const float4*)(x + ((size_t)(b * NN + n0)) * DD);
    #pragma unroll 8
    for (int i = 0; i < 32; i++) {
        int e = tid + (i << 8);           // 0..8191 float4s
        int row = e >> 9, f4 = e & 511;
        float4 v = xsrc[(size_t)row * 512 + f4];
        int c = f4 >> 1, h = f4 & 1;      // 16B chunk, half
        int sc = c ^ (row & 7);           // swizzle
        short4 s;
        s.x = f2bf(v.x); s.y = f2bf(v.y); s.z = f2bf(v.z); s.w = f2bf(v.w);
        *(short4*)&Xs[row * 2048 + sc * 8 + h * 4] = s;
    }
    __syncthreads();

    // ---- GEMM: wave w -> cols 16w..16w+15; B frag-packed, 1KB coalesced/iter ----
    const int lane = tid & 63, w = tid >> 6;
    const int mm = lane & 15, q = lane >> 4;
    const short* vp = Vp + (size_t)w * 32768 + lane * 8;
    const int arow = mm * 2048;
    const int msw = mm & 7;
    f32x4 acc = {0.f, 0.f, 0.f, 0.f};
    #pragma unroll 4
    for (int kc = 0; kc < 64; kc++) {
        bf16x8 a  = *(const bf16x8*)&Xs[arow + (((kc * 4 + q) ^ msw) << 3)];
        bf16x8 bv = *(const bf16x8*)(vp + kc * 512);
        acc = __builtin_amdgcn_mfma_f32_16x16x32_bf16(a, bv, acc, 0, 0, 0);
    }

    // ---- epilogue: dis rows ----
    const float wl = W[w * 16 + mm];
    float* dpb = dpart + blk * 64;
    #pragma unroll
    for (int r = 0; r < 4; r++) {
        float p = tanhf(acc[r]) * wl;
        p += __shfl_xor(p, 1, 64);
        p += __shfl_xor(p, 2, 64);
        p += __shfl_xor(p, 4, 64);
        p += __shfl_xor(p, 8, 64);
        if (mm == 0) dpb[w * 16 + q * 4 + r] = p;   // per-wave partial col-sum
    }
    __syncthreads();   // wave's global write drained (vmcnt) before barrier

    if (w == 0) {
        float d = (dpb[mm] + dpb[16 + mm] + dpb[32 + mm] + dpb[48 + mm]) * 0.125f;
        int n = n0 + mm;
        if (n >= tn) d = -1e20f;                    // in-tile masked rows
        if (lane < 16) dis[b * NN + n] = d;
        float mx = d;
        mx = fmaxf(mx, __shfl_xor(mx, 1, 64));
        mx = fmaxf(mx, __shfl_xor(mx, 2, 64));
        mx = fmaxf(mx, __shfl_xor(mx, 4, 64));
        mx = fmaxf(mx, __shfl_xor(mx, 8, 64));
        float e = expf(d - mx);                     // masked -> 0
        float ls = e;
        ls += __shfl_xor(ls, 1, 64);
        ls += __shfl_xor(ls, 2, 64);
        ls += __shfl_xor(ls, 4, 64);
        ls += __shfl_xor(ls, 8, 64);
        if (lane < 16) erow_g[blk * 16 + lane] = e;
        if (lane == 0) { mblk[blk] = mx; lblk[blk] = ls; }
    }
    __syncthreads();

    // ---- weighted partial for chunk d = 8*tid..8*tid+7, then dot with fc_w ----
    float er[16];
    const float* eg = erow_g + blk * 16;
    #pragma unroll
    for (int r = 0; r < 16; r++) er[r] = eg[r];

    float facc[8];
    #pragma unroll
    for (int u = 0; u < 8; u++) facc[u] = 0.f;
    #pragma unroll
    for (int r = 0; r < 16; r++) {
        bf16x8 sv = *(const bf16x8*)&Xs[r * 2048 + ((tid ^ (r & 7)) << 3)];
        float e = er[r];
        #pragma unroll
        for (int u = 0; u < 8; u++) facc[u] = fmaf(e, bf2f(sv[u]), facc[u]);
    }
    // q_c = sum_d facc_d * fc_w[c][d]  (linear in e; normalized later)
    const float4* w0p = (const float4*)fc_w + tid * 2;
    const float4* w1p = (const float4*)(fc_w + DD) + tid * 2;
    float4 wa = w0p[0], wb = w0p[1], wc = w1p[0], wd = w1p[1];
    float q0 = facc[0] * wa.x + facc[1] * wa.y + facc[2] * wa.z + facc[3] * wa.w +
               facc[4] * wb.x + facc[5] * wb.y + facc[6] * wb.z + facc[7] * wb.w;
    float q1 = facc[0] * wc.x + facc[1] * wc.y + facc[2] * wc.z + facc[3] * wc.w +
               facc[4] * wd.x + facc[5] * wd.y + facc[6] * wd.z + facc[7] * wd.w;
    #pragma unroll
    for (int o = 32; o >= 1; o >>= 1) {
        q0 += __shfl_xor(q0, o, 64);
        q1 += __shfl_xor(q1, o, 64);
    }
    if (lane == 0) {
        atomicAdd(&qblk[blk * 2 + 0], q0);
        atomicAdd(&qblk[blk * 2 + 1], q1);
    }
}

// ---- K2: per-batch: combine m/l -> M,L ; soft_assign ; logits -> cls ----
__global__ __launch_bounds__(256) void k_final(
        const float* __restrict__ dis, const int* __restrict__ tn_p,
        const float* __restrict__ mblk, const float* __restrict__ lblk,
        const float* __restrict__ qblk, const float* __restrict__ fc_b,
        float* __restrict__ soft, float* __restrict__ cls) {
    __shared__ float red[4];
    __shared__ float r3[3][4];
    __shared__ float bc;
    const int b = blockIdx.x, t = threadIdx.x;
    const int tn = tn_p[b];
    const int nvb = (tn + 15) >> 4;             // valid tiles, 1..256

    float mt = (t < nvb) ? mblk[b * 256 + t] : -3.4e38f;
    float mx = mt;
    #pragma unroll
    for (int o = 32; o >= 1; o >>= 1) mx = fmaxf(mx, __shfl_xor(mx, o, 64));
    if ((t & 63) == 0) red[t >> 6] = mx;
    __syncthreads();
    if (t == 0) bc = fmaxf(fmaxf(red[0], red[1]), fmaxf(red[2], red[3]));
    __syncthreads();
    const float M = bc;

    float sc = (t < nvb) ? expf(mt - M) : 0.f;
    float ls = (t < nvb) ? sc * lblk[b * 256 + t] : 0.f;
    float l0 = 0.f, l1 = 0.f;
    if (t < nvb) {
        l0 = sc * qblk[(b * 256 + t) * 2 + 0];
        l1 = sc * qblk[(b * 256 + t) * 2 + 1];
    }
    #pragma unroll
    for (int o = 32; o >= 1; o >>= 1) {
        ls += __shfl_xor(ls, o, 64);
        l0 += __shfl_xor(l0, o, 64);
        l1 += __shfl_xor(l1, o, 64);
    }
    if ((t & 63) == 0) {
        r3[0][t >> 6] = ls; r3[1][t >> 6] = l0; r3[2][t >> 6] = l1;
    }
    __syncthreads();
    if (t == 0) {
        float L  = r3[0][0] + r3[0][1] + r3[0][2] + r3[0][3];
        float Q0 = r3[1][0] + r3[1][1] + r3[1][2] + r3[1][3];
        float Q1 = r3[2][0] + r3[2][1] + r3[2][2] + r3[2][3];
        float L0 = Q0 / L + fc_b[0];
        float L1 = Q1 / L + fc_b[1];
        float mm2 = fmaxf(L0, L1);
        float e0 = expf(L0 - mm2), e1 = expf(L1 - mm2);
        float inv = 1.f / (e0 + e1);
        cls[b * 2 + 0] = e0 * inv;
        cls[b * 2 + 1] = e1 * inv;
        bc = 1.f / L;
    }
    __syncthreads();
    const float iL = bc;

    const float4* dv4 = (const float4*)(dis + (size_t)b * NN);
    float4* sv4 = (float4*)(soft + (size_t)b * NN);
    for (int i = t; i < NN / 4; i += 256) {
        int n = i * 4;
        float4 dv = dv4[i];
        float4 o;
        o.x = (n + 0 < tn) ? expf(dv.x - M) * iL : 0.f;
        o.y = (n + 1 < tn) ? expf(dv.y - M) * iL : 0.f;
        o.z = (n + 2 < tn) ? expf(dv.z - M) * iL : 0.f;
        o.w = (n + 3 < tn) ? expf(dv.w - M) * iL : 0.f;
        sv4[i] = o;
    }
}

extern "C" void kernel_launch(void* const* d_in, const int* in_sizes, int n_in,
                              void* d_out, int out_size, void* d_ws, size_t ws_size,
                              hipStream_t stream) {
    (void)in_sizes; (void)n_in; (void)out_size; (void)ws_size;
    const float* x        = (const float*)d_in[0];
    const int*   true_num = (const int*)d_in[1];
    const float* V        = (const float*)d_in[2];
    const float* W        = (const float*)d_in[3];
    const float* fc_w     = (const float*)d_in[4];
    const float* fc_b     = (const float*)d_in[5];

    float* out  = (float*)d_out;
    float* cls  = out;                     // B*NCLS = 16
    float* soft = out + BB * 2;            // B*N = 32768

    float* dis   = (float*)d_ws;                 // 32768
    float* mblk  = dis + (size_t)BB * NN;        // 2048
    float* lblk  = mblk + 2048;                  // 2048
    float* qblk  = lblk + 2048;                  // 4096
    float* dpart = qblk + 4096;                  // 2048*64
    float* erow  = dpart + (size_t)2048 * 64;    // 2048*16
    short* Vp    = (short*)(erow + (size_t)2048 * 16);  // 4*64*64*8 bf16 = 256 KiB

    k_pack_v<<<64, 256, 0, stream>>>(V, Vp, qblk);
    k_fused<<<2048, 256, 0, stream>>>(x, true_num, Vp, W, fc_w,
                                      dis, mblk, lblk, qblk, dpart, erow);
    k_final<<<BB, 256, 0, stream>>>(dis, true_num, mblk, lblk, qblk, fc_b,
                                    soft, cls);
}

// Round 4
// 343.186 us; speedup vs baseline: 1.3234x; 1.0466x over previous
//
#include <hip/hip_runtime.h>
#include <math.h>

#define BB 8
#define NN 4096
#define DD 2048

typedef __attribute__((ext_vector_type(8))) short bf16x8;
typedef __attribute__((ext_vector_type(4))) float f32x4;

// fp32 -> bf16 round-to-nearest-even (inputs are finite randoms; no NaN path)
__device__ __forceinline__ short f2bf(float f) {
    unsigned int u = __float_as_uint(f);
    unsigned int r = (u + 0x7fffu + ((u >> 16) & 1u)) >> 16;
    return (short)r;
}
__device__ __forceinline__ float bf2f(short s) {
    return __uint_as_float(((unsigned int)(unsigned short)s) << 16);
}

// ---- K0: pack V (2048x64 fp32) into MFMA B-frag order ----
// Vp[((w*64+kc)*64 + lane)*8 + j] = bf16(V[kc*32 + (lane>>4)*8 + j][w*16 + (lane&15)])
__global__ __launch_bounds__(256) void k_pack_v(const float* __restrict__ V,
                                                short* __restrict__ Vp) {
    int e = blockIdx.x * 256 + threadIdx.x;    // 0..16383
    int lane = e & 63, kc = (e >> 6) & 63, w = e >> 12;
    int q = lane >> 4, mm = lane & 15;
    int kb = kc * 32 + q * 8, l = w * 16 + mm;
    bf16x8 o;
    #pragma unroll
    for (int j = 0; j < 8; j++) o[j] = f2bf(V[(size_t)(kb + j) * 64 + l]);
    *(bf16x8*)(Vp + (size_t)e * 8) = o;
}

// ---- K1: fused dis-GEMM + block-local online-softmax + e-weighted q-dots ----
// grid 2048 (= B * N/16), 256 threads; x read ONCE (nontemporal); LDS bf16 tile.
__global__ __launch_bounds__(256, 2) void k_fused(
        const float* __restrict__ x, const int* __restrict__ tn_p,
        const short* __restrict__ Vp, const float* __restrict__ W,
        const float* __restrict__ fc_w,
        float* __restrict__ dis, float* __restrict__ mblk,
        float* __restrict__ lblk, float* __restrict__ qblk,
        float* __restrict__ dpart, float* __restrict__ erow_g) {
    __shared__ short Xs[16 * 2048];   // exactly 64 KiB -> 2 blocks/CU

    const int tid = threadIdx.x;
    const int blk = blockIdx.x;
    const int b  = blk >> 8;
    const int n0 = (blk & 255) << 4;
    const int tn = tn_p[b];
    if (n0 >= tn) return;             // fully-masked tile

    const int lane = tid & 63, w = tid >> 6;
    const int mm = lane & 15, q = lane >> 4;

    // ---- stage: 16 rows x 2048 fp32 -> bf16 LDS (nontemporal: x read once) ----
    const f32x4* xsrc = (const f32x4*)(x + ((size_t)(b * NN + n0)) * DD);
    #pragma unroll 8
    for (int i = 0; i < 32; i++) {
        int e = tid + (i << 8);           // 0..8191 float4s
        int row = e >> 9, f4 = e & 511;
        f32x4 v = __builtin_nontemporal_load(&xsrc[(size_t)row * 512 + f4]);
        int c = f4 >> 1, h = f4 & 1;      // 16B chunk, half
        int sc = c ^ (row & 7);           // swizzle
        short4 s;
        s.x = f2bf(v.x); s.y = f2bf(v.y); s.z = f2bf(v.z); s.w = f2bf(v.w);
        *(short4*)&Xs[row * 2048 + sc * 8 + h * 4] = s;
    }

    // B-frag prefetch (independent of LDS) + W load, issued under staging drain
    const bf16x8* vpv = (const bf16x8*)Vp + ((size_t)w << 12) + lane;
    bf16x8 bvr[4];
    #pragma unroll
    for (int j = 0; j < 4; j++) bvr[j] = vpv[j << 6];
    const float wl = W[w * 16 + mm];

    __syncthreads();

    // ---- GEMM: wave w -> cols 16w..16w+15; 4-deep B prefetch pipeline ----
    const int arow = mm * 2048;
    const int msw = mm & 7;
    f32x4 acc = {0.f, 0.f, 0.f, 0.f};
    #pragma unroll
    for (int kc = 0; kc < 64; kc += 4) {
        bf16x8 cur0 = bvr[0], cur1 = bvr[1], cur2 = bvr[2], cur3 = bvr[3];
        if (kc + 4 < 64) {
            #pragma unroll
            for (int j = 0; j < 4; j++) bvr[j] = vpv[(kc + 4 + j) << 6];
        }
        bf16x8 a0 = *(const bf16x8*)&Xs[arow + ((((kc + 0) * 4 + q) ^ msw) << 3)];
        acc = __builtin_amdgcn_mfma_f32_16x16x32_bf16(a0, cur0, acc, 0, 0, 0);
        bf16x8 a1 = *(const bf16x8*)&Xs[arow + ((((kc + 1) * 4 + q) ^ msw) << 3)];
        acc = __builtin_amdgcn_mfma_f32_16x16x32_bf16(a1, cur1, acc, 0, 0, 0);
        bf16x8 a2 = *(const bf16x8*)&Xs[arow + ((((kc + 2) * 4 + q) ^ msw) << 3)];
        acc = __builtin_amdgcn_mfma_f32_16x16x32_bf16(a2, cur2, acc, 0, 0, 0);
        bf16x8 a3 = *(const bf16x8*)&Xs[arow + ((((kc + 3) * 4 + q) ^ msw) << 3)];
        acc = __builtin_amdgcn_mfma_f32_16x16x32_bf16(a3, cur3, acc, 0, 0, 0);
    }

    // fc_w fragment loads early (overlap L2 latency with epilogue reductions)
    const float4* w0p = (const float4*)fc_w + tid * 2;
    const float4* w1p = (const float4*)(fc_w + DD) + tid * 2;
    float4 wa = w0p[0], wb = w0p[1], wc = w1p[0], wd = w1p[1];

    // ---- epilogue: dis rows; C layout col=lane&15, row=(lane>>4)*4+reg ----
    float* dpb = dpart + blk * 64;
    #pragma unroll
    for (int r = 0; r < 4; r++) {
        float p = tanhf(acc[r]) * wl;
        p += __shfl_xor(p, 1, 64);
        p += __shfl_xor(p, 2, 64);
        p += __shfl_xor(p, 4, 64);
        p += __shfl_xor(p, 8, 64);
        if (mm == 0) dpb[w * 16 + q * 4 + r] = p;   // per-wave partial col-sum
    }
    __syncthreads();   // wave's global write drained (vmcnt) before barrier

    if (w == 0) {
        float d = (dpb[mm] + dpb[16 + mm] + dpb[32 + mm] + dpb[48 + mm]) * 0.125f;
        int n = n0 + mm;
        if (n >= tn) d = -1e20f;                    // in-tile masked rows
        if (lane < 16) dis[b * NN + n] = d;
        float mx = d;
        mx = fmaxf(mx, __shfl_xor(mx, 1, 64));
        mx = fmaxf(mx, __shfl_xor(mx, 2, 64));
        mx = fmaxf(mx, __shfl_xor(mx, 4, 64));
        mx = fmaxf(mx, __shfl_xor(mx, 8, 64));
        float e = expf(d - mx);                     // masked -> 0
        float ls = e;
        ls += __shfl_xor(ls, 1, 64);
        ls += __shfl_xor(ls, 2, 64);
        ls += __shfl_xor(ls, 4, 64);
        ls += __shfl_xor(ls, 8, 64);
        if (lane < 16) erow_g[blk * 16 + lane] = e;
        if (lane == 0) { mblk[blk] = mx; lblk[blk] = ls; }
    }
    __syncthreads();

    // ---- weighted partial for chunk d = 8*tid..8*tid+7, dotted with fc_w ----
    float er[16];
    const float* eg = erow_g + blk * 16;
    #pragma unroll
    for (int r = 0; r < 16; r++) er[r] = eg[r];

    float facc[8];
    #pragma unroll
    for (int u = 0; u < 8; u++) facc[u] = 0.f;
    #pragma unroll
    for (int r = 0; r < 16; r++) {
        bf16x8 sv = *(const bf16x8*)&Xs[r * 2048 + ((tid ^ (r & 7)) << 3)];
        float e = er[r];
        #pragma unroll
        for (int u = 0; u < 8; u++) facc[u] = fmaf(e, bf2f(sv[u]), facc[u]);
    }
    float q0 = facc[0] * wa.x + facc[1] * wa.y + facc[2] * wa.z + facc[3] * wa.w +
               facc[4] * wb.x + facc[5] * wb.y + facc[6] * wb.z + facc[7] * wb.w;
    float q1 = facc[0] * wc.x + facc[1] * wc.y + facc[2] * wc.z + facc[3] * wc.w +
               facc[4] * wd.x + facc[5] * wd.y + facc[6] * wd.z + facc[7] * wd.w;
    #pragma unroll
    for (int o = 32; o >= 1; o >>= 1) {
        q0 += __shfl_xor(q0, o, 64);
        q1 += __shfl_xor(q1, o, 64);
    }
    if (lane == 0) {   // per-wave slot: no atomics, no zero-init needed
        qblk[blk * 8 + w * 2 + 0] = q0;
        qblk[blk * 8 + w * 2 + 1] = q1;
    }
}

// ---- K2: per-batch: combine m/l -> M,L ; soft_assign ; logits -> cls ----
// grid 32 = 8 batches x 4 slices; every slice recomputes M/L (cheap), slice 0 -> cls
__global__ __launch_bounds__(256) void k_final(
        const float* __restrict__ dis, const int* __restrict__ tn_p,
        const float* __restrict__ mblk, const float* __restrict__ lblk,
        const float* __restrict__ qblk, const float* __restrict__ fc_b,
        float* __restrict__ soft, float* __restrict__ cls) {
    __shared__ float red[4];
    __shared__ float r3[3][4];
    __shared__ float bc;
    const int b = blockIdx.x >> 2, s = blockIdx.x & 3, t = threadIdx.x;
    const int tn = tn_p[b];
    const int nvb = (tn + 15) >> 4;             // valid tiles, 1..256

    float mt = (t < nvb) ? mblk[b * 256 + t] : -3.4e38f;
    float mx = mt;
    #pragma unroll
    for (int o = 32; o >= 1; o >>= 1) mx = fmaxf(mx, __shfl_xor(mx, o, 64));
    if ((t & 63) == 0) red[t >> 6] = mx;
    __syncthreads();
    if (t == 0) bc = fmaxf(fmaxf(red[0], red[1]), fmaxf(red[2], red[3]));
    __syncthreads();
    const float M = bc;

    float sc = (t < nvb) ? expf(mt - M) : 0.f;
    float ls = (t < nvb) ? sc * lblk[b * 256 + t] : 0.f;
    float l0 = 0.f, l1 = 0.f;
    if (t < nvb) {
        const float* qp = qblk + (size_t)(b * 256 + t) * 8;
        l0 = sc * (qp[0] + qp[2] + qp[4] + qp[6]);
        l1 = sc * (qp[1] + qp[3] + qp[5] + qp[7]);
    }
    #pragma unroll
    for (int o = 32; o >= 1; o >>= 1) {
        ls += __shfl_xor(ls, o, 64);
        l0 += __shfl_xor(l0, o, 64);
        l1 += __shfl_xor(l1, o, 64);
    }
    if ((t & 63) == 0) {
        r3[0][t >> 6] = ls; r3[1][t >> 6] = l0; r3[2][t >> 6] = l1;
    }
    __syncthreads();
    if (t == 0) {
        float L  = r3[0][0] + r3[0][1] + r3[0][2] + r3[0][3];
        bc = 1.f / L;
        if (s == 0) {
            float Q0 = r3[1][0] + r3[1][1] + r3[1][2] + r3[1][3];
            float Q1 = r3[2][0] + r3[2][1] + r3[2][2] + r3[2][3];
            float L0 = Q0 / L + fc_b[0];
            float L1 = Q1 / L + fc_b[1];
            float mm2 = fmaxf(L0, L1);
            float e0 = expf(L0 - mm2), e1 = expf(L1 - mm2);
            float inv = 1.f / (e0 + e1);
            cls[b * 2 + 0] = e0 * inv;
            cls[b * 2 + 1] = e1 * inv;
        }
    }
    __syncthreads();
    const float iL = bc;

    // slice s covers 1024 elements = 256 float4s -> one per thread
    const int i = s * 256 + t;                  // float4 index within batch
    const int n = i * 4;
    float4 dv = ((const float4*)(dis + (size_t)b * NN))[i];
    float4 o;
    o.x = (n + 0 < tn) ? expf(dv.x - M) * iL : 0.f;
    o.y = (n + 1 < tn) ? expf(dv.y - M) * iL : 0.f;
    o.z = (n + 2 < tn) ? expf(dv.z - M) * iL : 0.f;
    o.w = (n + 3 < tn) ? expf(dv.w - M) * iL : 0.f;
    ((float4*)(soft + (size_t)b * NN))[i] = o;
}

extern "C" void kernel_launch(void* const* d_in, const int* in_sizes, int n_in,
                              void* d_out, int out_size, void* d_ws, size_t ws_size,
                              hipStream_t stream) {
    (void)in_sizes; (void)n_in; (void)out_size; (void)ws_size;
    const float* x        = (const float*)d_in[0];
    const int*   true_num = (const int*)d_in[1];
    const float* V        = (const float*)d_in[2];
    const float* W        = (const float*)d_in[3];
    const float* fc_w     = (const float*)d_in[4];
    const float* fc_b     = (const float*)d_in[5];

    float* out  = (float*)d_out;
    float* cls  = out;                     // B*NCLS = 16
    float* soft = out + BB * 2;            // B*N = 32768

    float* dis   = (float*)d_ws;                 // 32768
    float* mblk  = dis + (size_t)BB * NN;        // 2048
    float* lblk  = mblk + 2048;                  // 2048
    float* qblk  = lblk + 2048;                  // 2048*8
    float* dpart = qblk + (size_t)2048 * 8;      // 2048*64
    float* erow  = dpart + (size_t)2048 * 64;    // 2048*16
    short* Vp    = (short*)(erow + (size_t)2048 * 16);  // 4*64*64*8 bf16 = 256 KiB

    k_pack_v<<<64, 256, 0, stream>>>(V, Vp);
    k_fused<<<2048, 256, 0, stream>>>(x, true_num, Vp, W, fc_w,
                                      dis, mblk, lblk, qblk, dpart, erow);
    k_final<<<32, 256, 0, stream>>>(dis, true_num, mblk, lblk, qblk, fc_b,
                                    soft, cls);
}